// Round 7
// baseline (271.869 us; speedup 1.0000x reference)
//
#include <hip/hip_runtime.h>

// out[b,o] = BASE + WAVELET + bias
//   BASE    = sum_i silu(x[b,i]) * BW[o,i]      -> bf16 MFMA kernel (+bias)
//   WAVELET = sum_i ((xs^2-1)*exp(-xs^2/2))*WW  -> VALU kernel (KS=8 partials)
// then reduce: out += sum_k partial[k].
//
// Wavelet kernel = round-6 kernel (passed, 54us) minus the base branch:
// lsx/lb arrays, silu staging and the base acc fma deleted. Inner per k-pair:
// 4 pk + 2 v_exp = ~34 cyc/pair-group. LDS 25.6KB -> 6 blocks/CU.
// Per-(o,i) precompute: a2=C2/s^2, m1=-2*a2*t, m2'=a2*t^2-C2, q=w*2^C2/C2
//   p = a2*x^2 + m1*x + m2' (= C2*xs^2-C2);  term = q * p * 2^p

constexpr int IN_F  = 512;
constexpr int OUT_F = 512;
constexpr int BATCH = 1024;
constexpr int BT = 64, OT = 64;
constexpr int KS = 8;               // grid 16x8x8 = 1024 blocks
constexpr int KR = IN_F / KS;       // 64
constexpr int IT = 16;
constexpr int PITCH = IT + 4;
constexpr int NCH = KR / IT;        // 4
constexpr int BO  = BATCH * OUT_F;

#define LOG2E 1.44269504088897f
#define C2f   (-0.72134752044448f)
#define NC2f  ( 0.72134752044448f)
#define RQf   (-0.84083003f)   /* 2^C2 / C2 */

typedef float v2f   __attribute__((ext_vector_type(2)));
typedef float f32x4 __attribute__((ext_vector_type(4)));
typedef short short8 __attribute__((ext_vector_type(8)));

__device__ __forceinline__ float fexp2(float v) { return __builtin_amdgcn_exp2f(v); }
__device__ __forceinline__ float frcp(float v)  { return __builtin_amdgcn_rcpf(v); }
__device__ __forceinline__ v2f pkfma(v2f a, v2f b, v2f c) {
  return __builtin_elementwise_fma(a, b, c);
}
__device__ __forceinline__ float fsilu(float v) {
  return v * frcp(1.f + fexp2(v * -LOG2E));
}
__device__ __forceinline__ short bf16rne(float f) {
  unsigned u = __float_as_uint(f);
  return (short)((u + 0x7FFFu + ((u >> 16) & 1u)) >> 16);
}

// ---------------- wavelet kernel ----------------
__global__ __launch_bounds__(256, 6)
void wkan_main(const float* __restrict__ x,
               const float* __restrict__ wavew, const float* __restrict__ scale,
               const float* __restrict__ transl,
               float* __restrict__ partial, float* __restrict__ out, int use_ws)
{
  __shared__ float lx [BT * PITCH];
  __shared__ float la [OT * PITCH];
  __shared__ float lm [OT * PITCH];
  __shared__ float ln [OT * PITCH];
  __shared__ float lq [OT * PITCH];

  const int tid = threadIdx.x;
  const int b0 = blockIdx.x * BT;
  const int o0 = blockIdx.y * OT;
  const int ks = blockIdx.z;
  const int k0 = ks * KR;

  const int srow = tid >> 2;
  const int sc4  = (tid & 3) * 4;
  const int lofs = srow * PITCH + sc4;

  const int to = tid & 15;
  const int tb = tid >> 4;

  v2f zz; zz.x = 0.f; zz.y = 0.f;
  v2f acc[4][4];
#pragma unroll
  for (int r = 0; r < 4; ++r)
#pragma unroll
    for (int c = 0; c < 4; ++c) acc[r][c] = zz;

  for (int kc = 0; kc < NCH; ++kc) {
    const int g = k0 + kc * IT + sc4;
    __syncthreads();
    // ---------- stage chunk ----------
    {
      float4 xv = *(const float4*)(x + (size_t)(b0 + srow) * IN_F + g);
      *(float4*)(lx + lofs) = xv;

      float4 sv = *(const float4*)(scale  + (size_t)(o0 + srow) * IN_F + g);
      float4 tv = *(const float4*)(transl + (size_t)(o0 + srow) * IN_F + g);
      float4 av, mv, nv;
      {
        float a2, a2t;
        a2 = C2f * frcp(sv.x * sv.x); a2t = a2 * tv.x;
        av.x = a2; mv.x = -2.f * a2t; nv.x = fmaf(a2t, tv.x, NC2f);
        a2 = C2f * frcp(sv.y * sv.y); a2t = a2 * tv.y;
        av.y = a2; mv.y = -2.f * a2t; nv.y = fmaf(a2t, tv.y, NC2f);
        a2 = C2f * frcp(sv.z * sv.z); a2t = a2 * tv.z;
        av.z = a2; mv.z = -2.f * a2t; nv.z = fmaf(a2t, tv.z, NC2f);
        a2 = C2f * frcp(sv.w * sv.w); a2t = a2 * tv.w;
        av.w = a2; mv.w = -2.f * a2t; nv.w = fmaf(a2t, tv.w, NC2f);
      }
      *(float4*)(la + lofs) = av;
      *(float4*)(lm + lofs) = mv;
      *(float4*)(ln + lofs) = nv;

      float4 wv = *(const float4*)(wavew + (size_t)(o0 + srow) * IN_F + g);
      float4 qv;
      qv.x = wv.x * RQf; qv.y = wv.y * RQf; qv.z = wv.z * RQf; qv.w = wv.w * RQf;
      *(float4*)(lq + lofs) = qv;
    }
    __syncthreads();

    // ---------- compute: 4x4 outputs/thread ----------
    for (int ii = 0; ii < IT; ii += 4) {
      float4 xr[4], x2[4];
#pragma unroll
      for (int r = 0; r < 4; ++r) {
        const int row = (tb + 16 * r) * PITCH + ii;
        xr[r] = *(const float4*)(lx + row);
        x2[r].x = xr[r].x * xr[r].x;
        x2[r].y = xr[r].y * xr[r].y;
        x2[r].z = xr[r].z * xr[r].z;
        x2[r].w = xr[r].w * xr[r].w;
      }
#pragma unroll
      for (int c = 0; c < 4; ++c) {
        const int orow = (to + 16 * c) * PITCH + ii;
        float4 A = *(const float4*)(la + orow);
        float4 M = *(const float4*)(lm + orow);
        float4 N = *(const float4*)(ln + orow);
        float4 Q = *(const float4*)(lq + orow);
        v2f Al = {A.x, A.y}, Ah = {A.z, A.w};
        v2f Ml = {M.x, M.y}, Mh = {M.z, M.w};
        v2f Nl = {N.x, N.y}, Nh = {N.z, N.w};
        v2f Ql = {Q.x, Q.y}, Qh = {Q.z, Q.w};
#pragma unroll
        for (int r = 0; r < 4; ++r) {
          v2f xl  = {xr[r].x, xr[r].y}, xh  = {xr[r].z, xr[r].w};
          v2f x2l = {x2[r].x, x2[r].y}, x2h = {x2[r].z, x2[r].w};
          v2f p, e, gg;
          p = pkfma(Al, x2l, pkfma(Ml, xl, Nl));
          e.x = fexp2(p.x); e.y = fexp2(p.y);
          gg = p * Ql;
          acc[r][c] = pkfma(gg, e, acc[r][c]);
          p = pkfma(Ah, x2h, pkfma(Mh, xh, Nh));
          e.x = fexp2(p.x); e.y = fexp2(p.y);
          gg = p * Qh;
          acc[r][c] = pkfma(gg, e, acc[r][c]);
        }
      }
    }
  }

  // ---------- epilogue ----------
#pragma unroll
  for (int r = 0; r < 4; ++r) {
    const int br = b0 + tb + 16 * r;
#pragma unroll
    for (int c = 0; c < 4; ++c) {
      const int oc = o0 + to + 16 * c;
      float res = acc[r][c].x + acc[r][c].y;
      if (use_ws) {
        partial[(size_t)ks * BO + (size_t)br * OUT_F + oc] = res;
      } else {
        atomicAdd(out + (size_t)br * OUT_F + oc, res);  // out has base+bias
      }
    }
  }
}

// ---------------- base branch: bf16 MFMA GEMM (+bias) ----------------
// C[b,o] = sum_i silu(x[b,i]) * BW[o,i] + bias[o]
// One wave per 16x16 output tile; A,B frags loaded direct from global,
// silu+bf16 convert inline. Layouts per cdna_hip_programming.md §3:
//   A[m=lane&15][k=(lane>>4)*8+j], B[n=lane&15][k=(lane>>4)*8+j] (B^T form),
//   C/D: col=lane&15, row=(lane>>4)*4+reg.
__global__ __launch_bounds__(64)
void base_gemm(const float* __restrict__ x, const float* __restrict__ basew,
               const float* __restrict__ bias, float* __restrict__ out)
{
  const int lane = threadIdx.x;
  const int li  = lane & 15;
  const int quad = lane >> 4;
  const int bm = blockIdx.x * 16;   // batch
  const int bn = blockIdx.y * 16;   // out feature

  const float* arow = x     + (size_t)(bm + li) * IN_F + quad * 8;
  const float* brow = basew + (size_t)(bn + li) * IN_F + quad * 8;

  f32x4 acc = {0.f, 0.f, 0.f, 0.f};
  for (int k0 = 0; k0 < IN_F; k0 += 32) {
    float4 a0 = *(const float4*)(arow + k0);
    float4 a1 = *(const float4*)(arow + k0 + 4);
    float4 b0 = *(const float4*)(brow + k0);
    float4 b1 = *(const float4*)(brow + k0 + 4);
    short8 af, bfv;
    af[0] = bf16rne(fsilu(a0.x)); af[1] = bf16rne(fsilu(a0.y));
    af[2] = bf16rne(fsilu(a0.z)); af[3] = bf16rne(fsilu(a0.w));
    af[4] = bf16rne(fsilu(a1.x)); af[5] = bf16rne(fsilu(a1.y));
    af[6] = bf16rne(fsilu(a1.z)); af[7] = bf16rne(fsilu(a1.w));
    bfv[0] = bf16rne(b0.x); bfv[1] = bf16rne(b0.y);
    bfv[2] = bf16rne(b0.z); bfv[3] = bf16rne(b0.w);
    bfv[4] = bf16rne(b1.x); bfv[5] = bf16rne(b1.y);
    bfv[6] = bf16rne(b1.z); bfv[7] = bf16rne(b1.w);
    acc = __builtin_amdgcn_mfma_f32_16x16x32_bf16(af, bfv, acc, 0, 0, 0);
  }
  const float bi = bias[bn + li];
#pragma unroll
  for (int reg = 0; reg < 4; ++reg) {
    const int row = quad * 4 + reg;      // batch dim
    out[(size_t)(bm + row) * OUT_F + bn + li] = acc[reg] + bi;
  }
}

// ---------------- reduce: out += sum_k partial[k] ----------------
__global__ __launch_bounds__(256)
void wkan_reduce(const float* __restrict__ partial, float* __restrict__ out)
{
  const int i4 = (blockIdx.x * 256 + threadIdx.x) * 4;
  float4 r = *(const float4*)(out + i4);   // base + bias from base_gemm
#pragma unroll
  for (int k = 0; k < KS; ++k) {
    float4 a = *(const float4*)(partial + (size_t)k * BO + i4);
    r.x += a.x; r.y += a.y; r.z += a.z; r.w += a.w;
  }
  *(float4*)(out + i4) = r;
}

extern "C" void kernel_launch(void* const* d_in, const int* in_sizes, int n_in,
                              void* d_out, int out_size, void* d_ws, size_t ws_size,
                              hipStream_t stream) {
  const float* x  = (const float*)d_in[0];
  const float* bw = (const float*)d_in[1];
  const float* ww = (const float*)d_in[2];
  const float* sc = (const float*)d_in[3];
  const float* tr = (const float*)d_in[4];
  const float* bi = (const float*)d_in[5];
  float* out = (float*)d_out;

  const int use_ws = ws_size >= (size_t)KS * BO * sizeof(float) ? 1 : 0;

  // base branch + bias -> out (full overwrite; no memset needed)
  base_gemm<<<dim3(BATCH / 16, OUT_F / 16), dim3(64), 0, stream>>>(x, bw, bi, out);

  dim3 grid(BATCH / BT, OUT_F / OT, KS);  // 16 x 8 x 8 = 1024 blocks
  wkan_main<<<grid, dim3(256), 0, stream>>>(x, ww, sc, tr,
                                            (float*)d_ws, out, use_ws);
  if (use_ws) {
    wkan_reduce<<<dim3(BO / 1024), dim3(256), 0, stream>>>((const float*)d_ws, out);
  }
}

// Round 8
// 146.779 us; speedup vs baseline: 1.8522x; 1.8522x over previous
//
#include <hip/hip_runtime.h>

// out[b,o] = BASE + WAVELET + bias
//   BASE    = sum_i silu(x[b,i]) * BW[o,i]      -> bf16 MFMA kernel (+bias)
//   WAVELET = sum_i ((xs^2-1)*exp(-xs^2/2))*WW  -> VALU kernel (KS=8 partials)
// then reduce: out += sum_k partial[k].
//
// ROUND 8 = round 7 with ONE change: __launch_bounds__ (256,6)->(256,4).
// R7's (256,6) forced VGPR cap ~40 -> acc array spilled to scratch ->
// 900 MB/dispatch HBM spill traffic, VALUBusy 0.5%. NEVER request >4
// waves/EU here; let LDS (25.6KB -> 6 blocks/CU) provide occupancy.
//
// Per-(o,i) precompute: a2=C2/s^2, m1=-2*a2*t, m2'=a2*t^2-C2, q=w*2^C2/C2
//   p = a2*x^2 + m1*x + m2' (= C2*xs^2-C2);  term = q * p * 2^p

constexpr int IN_F  = 512;
constexpr int OUT_F = 512;
constexpr int BATCH = 1024;
constexpr int BT = 64, OT = 64;
constexpr int KS = 8;               // grid 16x8x8 = 1024 blocks
constexpr int KR = IN_F / KS;       // 64
constexpr int IT = 16;
constexpr int PITCH = IT + 4;
constexpr int NCH = KR / IT;        // 4
constexpr int BO  = BATCH * OUT_F;

#define LOG2E 1.44269504088897f
#define C2f   (-0.72134752044448f)
#define NC2f  ( 0.72134752044448f)
#define RQf   (-0.84083003f)   /* 2^C2 / C2 */

typedef float v2f   __attribute__((ext_vector_type(2)));
typedef float f32x4 __attribute__((ext_vector_type(4)));
typedef short short8 __attribute__((ext_vector_type(8)));

__device__ __forceinline__ float fexp2(float v) { return __builtin_amdgcn_exp2f(v); }
__device__ __forceinline__ float frcp(float v)  { return __builtin_amdgcn_rcpf(v); }
__device__ __forceinline__ v2f pkfma(v2f a, v2f b, v2f c) {
  return __builtin_elementwise_fma(a, b, c);
}
__device__ __forceinline__ float fsilu(float v) {
  return v * frcp(1.f + fexp2(v * -LOG2E));
}
__device__ __forceinline__ short bf16rne(float f) {
  unsigned u = __float_as_uint(f);
  return (short)((u + 0x7FFFu + ((u >> 16) & 1u)) >> 16);
}

// ---------------- wavelet kernel ----------------
__global__ __launch_bounds__(256, 4)
void wkan_main(const float* __restrict__ x,
               const float* __restrict__ wavew, const float* __restrict__ scale,
               const float* __restrict__ transl,
               float* __restrict__ partial, float* __restrict__ out, int use_ws)
{
  __shared__ float lx [BT * PITCH];
  __shared__ float la [OT * PITCH];
  __shared__ float lm [OT * PITCH];
  __shared__ float ln [OT * PITCH];
  __shared__ float lq [OT * PITCH];

  const int tid = threadIdx.x;
  const int b0 = blockIdx.x * BT;
  const int o0 = blockIdx.y * OT;
  const int ks = blockIdx.z;
  const int k0 = ks * KR;

  const int srow = tid >> 2;
  const int sc4  = (tid & 3) * 4;
  const int lofs = srow * PITCH + sc4;

  const int to = tid & 15;
  const int tb = tid >> 4;

  v2f zz; zz.x = 0.f; zz.y = 0.f;
  v2f acc[4][4];
#pragma unroll
  for (int r = 0; r < 4; ++r)
#pragma unroll
    for (int c = 0; c < 4; ++c) acc[r][c] = zz;

  for (int kc = 0; kc < NCH; ++kc) {
    const int g = k0 + kc * IT + sc4;
    __syncthreads();
    // ---------- stage chunk ----------
    {
      float4 xv = *(const float4*)(x + (size_t)(b0 + srow) * IN_F + g);
      *(float4*)(lx + lofs) = xv;

      float4 sv = *(const float4*)(scale  + (size_t)(o0 + srow) * IN_F + g);
      float4 tv = *(const float4*)(transl + (size_t)(o0 + srow) * IN_F + g);
      float4 av, mv, nv;
      {
        float a2, a2t;
        a2 = C2f * frcp(sv.x * sv.x); a2t = a2 * tv.x;
        av.x = a2; mv.x = -2.f * a2t; nv.x = fmaf(a2t, tv.x, NC2f);
        a2 = C2f * frcp(sv.y * sv.y); a2t = a2 * tv.y;
        av.y = a2; mv.y = -2.f * a2t; nv.y = fmaf(a2t, tv.y, NC2f);
        a2 = C2f * frcp(sv.z * sv.z); a2t = a2 * tv.z;
        av.z = a2; mv.z = -2.f * a2t; nv.z = fmaf(a2t, tv.z, NC2f);
        a2 = C2f * frcp(sv.w * sv.w); a2t = a2 * tv.w;
        av.w = a2; mv.w = -2.f * a2t; nv.w = fmaf(a2t, tv.w, NC2f);
      }
      *(float4*)(la + lofs) = av;
      *(float4*)(lm + lofs) = mv;
      *(float4*)(ln + lofs) = nv;

      float4 wv = *(const float4*)(wavew + (size_t)(o0 + srow) * IN_F + g);
      float4 qv;
      qv.x = wv.x * RQf; qv.y = wv.y * RQf; qv.z = wv.z * RQf; qv.w = wv.w * RQf;
      *(float4*)(lq + lofs) = qv;
    }
    __syncthreads();

    // ---------- compute: 4x4 outputs/thread ----------
    for (int ii = 0; ii < IT; ii += 4) {
      float4 xr[4], x2[4];
#pragma unroll
      for (int r = 0; r < 4; ++r) {
        const int row = (tb + 16 * r) * PITCH + ii;
        xr[r] = *(const float4*)(lx + row);
        x2[r].x = xr[r].x * xr[r].x;
        x2[r].y = xr[r].y * xr[r].y;
        x2[r].z = xr[r].z * xr[r].z;
        x2[r].w = xr[r].w * xr[r].w;
      }
#pragma unroll
      for (int c = 0; c < 4; ++c) {
        const int orow = (to + 16 * c) * PITCH + ii;
        float4 A = *(const float4*)(la + orow);
        float4 M = *(const float4*)(lm + orow);
        float4 N = *(const float4*)(ln + orow);
        float4 Q = *(const float4*)(lq + orow);
        v2f Al = {A.x, A.y}, Ah = {A.z, A.w};
        v2f Ml = {M.x, M.y}, Mh = {M.z, M.w};
        v2f Nl = {N.x, N.y}, Nh = {N.z, N.w};
        v2f Ql = {Q.x, Q.y}, Qh = {Q.z, Q.w};
#pragma unroll
        for (int r = 0; r < 4; ++r) {
          v2f xl  = {xr[r].x, xr[r].y}, xh  = {xr[r].z, xr[r].w};
          v2f x2l = {x2[r].x, x2[r].y}, x2h = {x2[r].z, x2[r].w};
          v2f p, e, gg;
          p = pkfma(Al, x2l, pkfma(Ml, xl, Nl));
          e.x = fexp2(p.x); e.y = fexp2(p.y);
          gg = p * Ql;
          acc[r][c] = pkfma(gg, e, acc[r][c]);
          p = pkfma(Ah, x2h, pkfma(Mh, xh, Nh));
          e.x = fexp2(p.x); e.y = fexp2(p.y);
          gg = p * Qh;
          acc[r][c] = pkfma(gg, e, acc[r][c]);
        }
      }
    }
  }

  // ---------- epilogue ----------
#pragma unroll
  for (int r = 0; r < 4; ++r) {
    const int br = b0 + tb + 16 * r;
#pragma unroll
    for (int c = 0; c < 4; ++c) {
      const int oc = o0 + to + 16 * c;
      float res = acc[r][c].x + acc[r][c].y;
      if (use_ws) {
        partial[(size_t)ks * BO + (size_t)br * OUT_F + oc] = res;
      } else {
        atomicAdd(out + (size_t)br * OUT_F + oc, res);  // out has base+bias
      }
    }
  }
}

// ---------------- base branch: bf16 MFMA GEMM (+bias) ----------------
// C[b,o] = sum_i silu(x[b,i]) * BW[o,i] + bias[o]
// Layouts per cdna_hip_programming.md §3 (verified in R7: passed).
__global__ __launch_bounds__(64)
void base_gemm(const float* __restrict__ x, const float* __restrict__ basew,
               const float* __restrict__ bias, float* __restrict__ out)
{
  const int lane = threadIdx.x;
  const int li  = lane & 15;
  const int quad = lane >> 4;
  const int bm = blockIdx.x * 16;   // batch
  const int bn = blockIdx.y * 16;   // out feature

  const float* arow = x     + (size_t)(bm + li) * IN_F + quad * 8;
  const float* brow = basew + (size_t)(bn + li) * IN_F + quad * 8;

  f32x4 acc = {0.f, 0.f, 0.f, 0.f};
  for (int k0 = 0; k0 < IN_F; k0 += 32) {
    float4 a0 = *(const float4*)(arow + k0);
    float4 a1 = *(const float4*)(arow + k0 + 4);
    float4 b0 = *(const float4*)(brow + k0);
    float4 b1 = *(const float4*)(brow + k0 + 4);
    short8 af, bfv;
    af[0] = bf16rne(fsilu(a0.x)); af[1] = bf16rne(fsilu(a0.y));
    af[2] = bf16rne(fsilu(a0.z)); af[3] = bf16rne(fsilu(a0.w));
    af[4] = bf16rne(fsilu(a1.x)); af[5] = bf16rne(fsilu(a1.y));
    af[6] = bf16rne(fsilu(a1.z)); af[7] = bf16rne(fsilu(a1.w));
    bfv[0] = bf16rne(b0.x); bfv[1] = bf16rne(b0.y);
    bfv[2] = bf16rne(b0.z); bfv[3] = bf16rne(b0.w);
    bfv[4] = bf16rne(b1.x); bfv[5] = bf16rne(b1.y);
    bfv[6] = bf16rne(b1.z); bfv[7] = bf16rne(b1.w);
    acc = __builtin_amdgcn_mfma_f32_16x16x32_bf16(af, bfv, acc, 0, 0, 0);
  }
  const float bi = bias[bn + li];
#pragma unroll
  for (int reg = 0; reg < 4; ++reg) {
    const int row = quad * 4 + reg;      // batch dim
    out[(size_t)(bm + row) * OUT_F + bn + li] = acc[reg] + bi;
  }
}

// ---------------- reduce: out += sum_k partial[k] ----------------
__global__ __launch_bounds__(256)
void wkan_reduce(const float* __restrict__ partial, float* __restrict__ out)
{
  const int i4 = (blockIdx.x * 256 + threadIdx.x) * 4;
  float4 r = *(const float4*)(out + i4);   // base + bias from base_gemm
#pragma unroll
  for (int k = 0; k < KS; ++k) {
    float4 a = *(const float4*)(partial + (size_t)k * BO + i4);
    r.x += a.x; r.y += a.y; r.z += a.z; r.w += a.w;
  }
  *(float4*)(out + i4) = r;
}

extern "C" void kernel_launch(void* const* d_in, const int* in_sizes, int n_in,
                              void* d_out, int out_size, void* d_ws, size_t ws_size,
                              hipStream_t stream) {
  const float* x  = (const float*)d_in[0];
  const float* bw = (const float*)d_in[1];
  const float* ww = (const float*)d_in[2];
  const float* sc = (const float*)d_in[3];
  const float* tr = (const float*)d_in[4];
  const float* bi = (const float*)d_in[5];
  float* out = (float*)d_out;

  const int use_ws = ws_size >= (size_t)KS * BO * sizeof(float) ? 1 : 0;

  // base branch + bias -> out (full overwrite; no memset needed)
  base_gemm<<<dim3(BATCH / 16, OUT_F / 16), dim3(64), 0, stream>>>(x, bw, bi, out);

  dim3 grid(BATCH / BT, OUT_F / OT, KS);  // 16 x 8 x 8 = 1024 blocks
  wkan_main<<<grid, dim3(256), 0, stream>>>(x, ww, sc, tr,
                                            (float*)d_ws, out, use_ws);
  if (use_ws) {
    wkan_reduce<<<dim3(BO / 1024), dim3(256), 0, stream>>>((const float*)d_ws, out);
  }
}

// Round 9
// 125.474 us; speedup vs baseline: 2.1667x; 1.1698x over previous
//
#include <hip/hip_runtime.h>

// out[b,o] = BASE + WAVELET + bias
//   WAVELET -> VALU kernel (KS=8 partials)  [launched FIRST]
//   BASE    -> bf16 MFMA kernel (+bias)
//   reduce: out += sum_k partial[k]
//
// ROUND 9 = R8 bodies unchanged; three dispatch/alloc changes:
//  - wkan_main __launch_bounds__(256,3): VGPR cap 170 -> allocator cannot
//    silently spill to chase the 8-waves/EU tier (R8 anomaly suspect #1)
//  - wkan_main launched first: window decoupled from base_gemm's L2 dirt /
//    harness poison drain (suspect #3)
//  - base_gemm grid bn-inner: consecutive blocks share x rows in L2

constexpr int IN_F  = 512;
constexpr int OUT_F = 512;
constexpr int BATCH = 1024;
constexpr int BT = 64, OT = 64;
constexpr int KS = 8;               // grid 16x8x8 = 1024 blocks
constexpr int KR = IN_F / KS;       // 64
constexpr int IT = 16;
constexpr int PITCH = IT + 4;
constexpr int NCH = KR / IT;        // 4
constexpr int BO  = BATCH * OUT_F;

#define LOG2E 1.44269504088897f
#define C2f   (-0.72134752044448f)
#define NC2f  ( 0.72134752044448f)
#define RQf   (-0.84083003f)   /* 2^C2 / C2 */

typedef float v2f   __attribute__((ext_vector_type(2)));
typedef float f32x4 __attribute__((ext_vector_type(4)));
typedef short short8 __attribute__((ext_vector_type(8)));

__device__ __forceinline__ float fexp2(float v) { return __builtin_amdgcn_exp2f(v); }
__device__ __forceinline__ float frcp(float v)  { return __builtin_amdgcn_rcpf(v); }
__device__ __forceinline__ v2f pkfma(v2f a, v2f b, v2f c) {
  return __builtin_elementwise_fma(a, b, c);
}
__device__ __forceinline__ float fsilu(float v) {
  return v * frcp(1.f + fexp2(v * -LOG2E));
}
__device__ __forceinline__ short bf16rne(float f) {
  unsigned u = __float_as_uint(f);
  return (short)((u + 0x7FFFu + ((u >> 16) & 1u)) >> 16);
}

// ---------------- wavelet kernel ----------------
__global__ __launch_bounds__(256, 3)
void wkan_main(const float* __restrict__ x,
               const float* __restrict__ wavew, const float* __restrict__ scale,
               const float* __restrict__ transl,
               float* __restrict__ partial, float* __restrict__ out, int use_ws)
{
  __shared__ float lx [BT * PITCH];
  __shared__ float la [OT * PITCH];
  __shared__ float lm [OT * PITCH];
  __shared__ float ln [OT * PITCH];
  __shared__ float lq [OT * PITCH];

  const int tid = threadIdx.x;
  const int b0 = blockIdx.x * BT;
  const int o0 = blockIdx.y * OT;
  const int ks = blockIdx.z;
  const int k0 = ks * KR;

  const int srow = tid >> 2;
  const int sc4  = (tid & 3) * 4;
  const int lofs = srow * PITCH + sc4;

  const int to = tid & 15;
  const int tb = tid >> 4;

  v2f zz; zz.x = 0.f; zz.y = 0.f;
  v2f acc[4][4];
#pragma unroll
  for (int r = 0; r < 4; ++r)
#pragma unroll
    for (int c = 0; c < 4; ++c) acc[r][c] = zz;

  for (int kc = 0; kc < NCH; ++kc) {
    const int g = k0 + kc * IT + sc4;
    __syncthreads();
    // ---------- stage chunk ----------
    {
      float4 xv = *(const float4*)(x + (size_t)(b0 + srow) * IN_F + g);
      *(float4*)(lx + lofs) = xv;

      float4 sv = *(const float4*)(scale  + (size_t)(o0 + srow) * IN_F + g);
      float4 tv = *(const float4*)(transl + (size_t)(o0 + srow) * IN_F + g);
      float4 av, mv, nv;
      {
        float a2, a2t;
        a2 = C2f * frcp(sv.x * sv.x); a2t = a2 * tv.x;
        av.x = a2; mv.x = -2.f * a2t; nv.x = fmaf(a2t, tv.x, NC2f);
        a2 = C2f * frcp(sv.y * sv.y); a2t = a2 * tv.y;
        av.y = a2; mv.y = -2.f * a2t; nv.y = fmaf(a2t, tv.y, NC2f);
        a2 = C2f * frcp(sv.z * sv.z); a2t = a2 * tv.z;
        av.z = a2; mv.z = -2.f * a2t; nv.z = fmaf(a2t, tv.z, NC2f);
        a2 = C2f * frcp(sv.w * sv.w); a2t = a2 * tv.w;
        av.w = a2; mv.w = -2.f * a2t; nv.w = fmaf(a2t, tv.w, NC2f);
      }
      *(float4*)(la + lofs) = av;
      *(float4*)(lm + lofs) = mv;
      *(float4*)(ln + lofs) = nv;

      float4 wv = *(const float4*)(wavew + (size_t)(o0 + srow) * IN_F + g);
      float4 qv;
      qv.x = wv.x * RQf; qv.y = wv.y * RQf; qv.z = wv.z * RQf; qv.w = wv.w * RQf;
      *(float4*)(lq + lofs) = qv;
    }
    __syncthreads();

    // ---------- compute: 4x4 outputs/thread ----------
    for (int ii = 0; ii < IT; ii += 4) {
      float4 xr[4], x2[4];
#pragma unroll
      for (int r = 0; r < 4; ++r) {
        const int row = (tb + 16 * r) * PITCH + ii;
        xr[r] = *(const float4*)(lx + row);
        x2[r].x = xr[r].x * xr[r].x;
        x2[r].y = xr[r].y * xr[r].y;
        x2[r].z = xr[r].z * xr[r].z;
        x2[r].w = xr[r].w * xr[r].w;
      }
#pragma unroll
      for (int c = 0; c < 4; ++c) {
        const int orow = (to + 16 * c) * PITCH + ii;
        float4 A = *(const float4*)(la + orow);
        float4 M = *(const float4*)(lm + orow);
        float4 N = *(const float4*)(ln + orow);
        float4 Q = *(const float4*)(lq + orow);
        v2f Al = {A.x, A.y}, Ah = {A.z, A.w};
        v2f Ml = {M.x, M.y}, Mh = {M.z, M.w};
        v2f Nl = {N.x, N.y}, Nh = {N.z, N.w};
        v2f Ql = {Q.x, Q.y}, Qh = {Q.z, Q.w};
#pragma unroll
        for (int r = 0; r < 4; ++r) {
          v2f xl  = {xr[r].x, xr[r].y}, xh  = {xr[r].z, xr[r].w};
          v2f x2l = {x2[r].x, x2[r].y}, x2h = {x2[r].z, x2[r].w};
          v2f p, e, gg;
          p = pkfma(Al, x2l, pkfma(Ml, xl, Nl));
          e.x = fexp2(p.x); e.y = fexp2(p.y);
          gg = p * Ql;
          acc[r][c] = pkfma(gg, e, acc[r][c]);
          p = pkfma(Ah, x2h, pkfma(Mh, xh, Nh));
          e.x = fexp2(p.x); e.y = fexp2(p.y);
          gg = p * Qh;
          acc[r][c] = pkfma(gg, e, acc[r][c]);
        }
      }
    }
  }

  // ---------- epilogue ----------
#pragma unroll
  for (int r = 0; r < 4; ++r) {
    const int br = b0 + tb + 16 * r;
#pragma unroll
    for (int c = 0; c < 4; ++c) {
      const int oc = o0 + to + 16 * c;
      float res = acc[r][c].x + acc[r][c].y;
      if (use_ws) {
        partial[(size_t)ks * BO + (size_t)br * OUT_F + oc] = res;
      } else {
        atomicAdd(out + (size_t)br * OUT_F + oc, res);  // out has base+bias
      }
    }
  }
}

// ---------------- base branch: bf16 MFMA GEMM (+bias) ----------------
// grid: x = out-feature tiles (inner), y = batch tiles -> consecutive
// blocks share the same x rows (L2 reuse), sweep basew.
__global__ __launch_bounds__(64)
void base_gemm(const float* __restrict__ x, const float* __restrict__ basew,
               const float* __restrict__ bias, float* __restrict__ out)
{
  const int lane = threadIdx.x;
  const int li  = lane & 15;
  const int quad = lane >> 4;
  const int bn = blockIdx.x * 16;   // out feature (inner)
  const int bm = blockIdx.y * 16;   // batch

  const float* arow = x     + (size_t)(bm + li) * IN_F + quad * 8;
  const float* brow = basew + (size_t)(bn + li) * IN_F + quad * 8;

  f32x4 acc = {0.f, 0.f, 0.f, 0.f};
  for (int k0 = 0; k0 < IN_F; k0 += 32) {
    float4 a0 = *(const float4*)(arow + k0);
    float4 a1 = *(const float4*)(arow + k0 + 4);
    float4 b0 = *(const float4*)(brow + k0);
    float4 b1 = *(const float4*)(brow + k0 + 4);
    short8 af, bfv;
    af[0] = bf16rne(fsilu(a0.x)); af[1] = bf16rne(fsilu(a0.y));
    af[2] = bf16rne(fsilu(a0.z)); af[3] = bf16rne(fsilu(a0.w));
    af[4] = bf16rne(fsilu(a1.x)); af[5] = bf16rne(fsilu(a1.y));
    af[6] = bf16rne(fsilu(a1.z)); af[7] = bf16rne(fsilu(a1.w));
    bfv[0] = bf16rne(b0.x); bfv[1] = bf16rne(b0.y);
    bfv[2] = bf16rne(b0.z); bfv[3] = bf16rne(b0.w);
    bfv[4] = bf16rne(b1.x); bfv[5] = bf16rne(b1.y);
    bfv[6] = bf16rne(b1.z); bfv[7] = bf16rne(b1.w);
    acc = __builtin_amdgcn_mfma_f32_16x16x32_bf16(af, bfv, acc, 0, 0, 0);
  }
  const float bi = bias[bn + li];
#pragma unroll
  for (int reg = 0; reg < 4; ++reg) {
    const int row = quad * 4 + reg;      // batch dim
    out[(size_t)(bm + row) * OUT_F + bn + li] = acc[reg] + bi;
  }
}

// ---------------- reduce: out += sum_k partial[k] ----------------
__global__ __launch_bounds__(256)
void wkan_reduce(const float* __restrict__ partial, float* __restrict__ out)
{
  const int i4 = (blockIdx.x * 256 + threadIdx.x) * 4;
  float4 r = *(const float4*)(out + i4);   // base + bias from base_gemm
#pragma unroll
  for (int k = 0; k < KS; ++k) {
    float4 a = *(const float4*)(partial + (size_t)k * BO + i4);
    r.x += a.x; r.y += a.y; r.z += a.z; r.w += a.w;
  }
  *(float4*)(out + i4) = r;
}

extern "C" void kernel_launch(void* const* d_in, const int* in_sizes, int n_in,
                              void* d_out, int out_size, void* d_ws, size_t ws_size,
                              hipStream_t stream) {
  const float* x  = (const float*)d_in[0];
  const float* bw = (const float*)d_in[1];
  const float* ww = (const float*)d_in[2];
  const float* sc = (const float*)d_in[3];
  const float* tr = (const float*)d_in[4];
  const float* bi = (const float*)d_in[5];
  float* out = (float*)d_out;

  const int use_ws = ws_size >= (size_t)KS * BO * sizeof(float) ? 1 : 0;
  if (!use_ws) {
    hipMemsetAsync(d_out, 0, (size_t)out_size * sizeof(float), stream);
  }

  // wavelet FIRST (clean memory window), then base, then reduce
  dim3 grid(BATCH / BT, OUT_F / OT, KS);  // 16 x 8 x 8 = 1024 blocks
  wkan_main<<<grid, dim3(256), 0, stream>>>(x, ww, sc, tr,
                                            (float*)d_ws, out, use_ws);

  base_gemm<<<dim3(OUT_F / 16, BATCH / 16), dim3(64), 0, stream>>>(x, bw, bi, out);

  if (use_ws) {
    wkan_reduce<<<dim3(BO / 1024), dim3(256), 0, stream>>>((const float*)d_ws, out);
  }
}